// Round 6
// baseline (268.516 us; speedup 1.0000x reference)
//
#include <hip/hip_runtime.h>
#include <hip/hip_bf16.h>
#include <hip/hip_cooperative_groups.h>

namespace cg = cooperative_groups;

typedef __attribute__((ext_vector_type(8))) short short8;
typedef __attribute__((ext_vector_type(4))) short short4v;
typedef __attribute__((ext_vector_type(4))) float floatx4;

#define SEQ   2048
#define EMB   1024
#define HEAD  64
#define BATCH 8

__device__ __forceinline__ short f2bf(float f) {
    union { float f; unsigned u; } a; a.f = f;
    unsigned u = a.u;
    u = (u + 0x7FFFu + ((u >> 16) & 1u)) >> 16;   // round-to-nearest-even
    return (short)u;
}

// One cooperative kernel, 3 phases separated by grid.sync():
//  P1: W [EMB][HEAD] fp32 -> Wf MFMA-fragment-ordered bf16
//  P2: qkv projections (MFMA), q/k row-major bf16, V transposed [B][H][S]
//  P3: causal flash attention, fixed-base softmax exp(s/8-16)
__global__ __launch_bounds__(256, 2) void fused_kernel(
        const float* __restrict__ x,  const float* __restrict__ Wk,
        const float* __restrict__ Wq, const float* __restrict__ Wv,
        float* __restrict__ out,      short* __restrict__ Wf,
        short* __restrict__ q,        short* __restrict__ k,
        short* __restrict__ vt) {
    __shared__ __align__(16) char smem[25600];
    cg::grid_group grid = cg::this_grid();

    const int tid  = threadIdx.x;
    const int bx   = blockIdx.x;       // 0..511
    const int wv   = tid >> 6;
    const int lane = tid & 63;
    const int l15  = lane & 15;
    const int quad = lane >> 4;

    // ================= P1: weight transpose/pack =================
    // Wf[f*512 + lane*8 + j] = W[k = chunk*32 + (lane>>4)*8 + j][h = nt*16 + (lane&15)]
    // f = (mat*4 + nt)*32 + chunk
    {
        int gid = bx * 256 + tid;
        if (gid < 24576) {
            int lane2 = gid & 63;
            int fid   = gid >> 6;
            int chunk = fid & 31;
            int mnt   = fid >> 5;
            int mat   = mnt >> 2, nt = mnt & 3;
            const float* src = (mat == 0) ? Wq : (mat == 1) ? Wk : Wv;
            int n = lane2 & 15, qd = lane2 >> 4;
            int h = nt * 16 + n;
            short8 o8;
            #pragma unroll
            for (int j = 0; j < 8; ++j)
                o8[j] = f2bf(src[(chunk * 32 + qd * 8 + j) * 64 + h]);
            *(short8*)(Wf + (long)gid * 8) = o8;
        }
    }
    grid.sync();

    // ================= P2: QKV projection =================
    // Block: 32 rows. Waves (0,1): rows 0-15 K-halves (0,1); (2,3): rows 16-31.
    {
        float (*red)[64][50] = (float (*)[64][50])smem;   // 25600 B
        const int rowg  = (wv >> 1) * 16;
        const int khalf = wv & 1;
        const int row0  = bx * 32 + rowg;

        floatx4 acc[12];
        #pragma unroll
        for (int f = 0; f < 12; ++f) acc[f] = (floatx4){0.f, 0.f, 0.f, 0.f};

        const float* xrow  = x + (long)(row0 + l15) * EMB + quad * 8;
        const short* wlane = Wf + (long)lane * 8;
        const int kbase = khalf * 512;

        floatx4 xa = *(const floatx4*)(xrow + kbase);
        floatx4 xb = *(const floatx4*)(xrow + kbase + 4);

        #pragma unroll 1
        for (int kk = 0; kk < 512; kk += 32) {
            const int cidx = (kbase + kk) >> 5;
            short8 bfr[12];
            #pragma unroll
            for (int f = 0; f < 12; ++f)
                bfr[f] = *(const short8*)(wlane + (long)(f * 32 + cidx) * 512);
            const int kn = kbase + ((kk + 32) & 511);   // wraps: safe, cached
            floatx4 na = *(const floatx4*)(xrow + kn);
            floatx4 nb = *(const floatx4*)(xrow + kn + 4);

            short8 a;
            #pragma unroll
            for (int i = 0; i < 4; ++i) { a[i] = f2bf(xa[i]); a[4 + i] = f2bf(xb[i]); }
            #pragma unroll
            for (int f = 0; f < 12; ++f)
                acc[f] = __builtin_amdgcn_mfma_f32_16x16x32_bf16(a, bfr[f], acc[f], 0, 0, 0);
            xa = na; xb = nb;
        }

        if (khalf == 1) {
            #pragma unroll
            for (int f = 0; f < 12; ++f)
                #pragma unroll
                for (int r = 0; r < 4; ++r)
                    red[wv >> 1][lane][f * 4 + r] = acc[f][r];
        }
        __syncthreads();
        if (khalf == 0) {
            #pragma unroll
            for (int f = 0; f < 12; ++f)
                #pragma unroll
                for (int r = 0; r < 4; ++r)
                    acc[f][r] += red[wv >> 1][lane][f * 4 + r];

            const int bidx = row0 >> 11;
            const int srow = (row0 & (SEQ - 1)) + quad * 4;
            #pragma unroll
            for (int nt = 0; nt < 4; ++nt) {
                const int col = nt * 16 + l15;
                #pragma unroll
                for (int r = 0; r < 4; ++r) {
                    long grow = (long)(row0 + quad * 4 + r);
                    q[grow * HEAD + col] = f2bf(acc[nt][r]);
                    k[grow * HEAD + col] = f2bf(acc[4 + nt][r]);
                }
                short4v vv;
                #pragma unroll
                for (int r = 0; r < 4; ++r) vv[r] = f2bf(acc[8 + nt][r]);
                *(short4v*)(vt + ((long)bidx * HEAD + col) * SEQ + srow) = vv;
            }
        }
    }
    grid.sync();

    // ================= P3: causal flash attention =================
    // Block handles tiles (pr, 127-pr) of batch b: balanced ~65 chunks total,
    // 4 waves key-split per tile, fixed-base softmax exp(s/8-16) (row-max>=0
    // via causal diagonal; base cancels in sum(pV)/sum(p)).
    {
        short (*Plds)[16][40] = (short (*)[16][40])smem;          // 5120 B
        float (*oA)[16][64]   = (float (*)[16][64])(smem + 5120); // 16384 B
        float (*lA)[16]       = (float (*)[16])(smem + 21504);    // 256 B
        const int b  = bx & 7;
        const int pr = bx >> 3;

        const short* kbb = k  + ((long)b * SEQ  + l15) * HEAD + quad * 8;
        const short* vbb = vt + ((long)b * HEAD + l15) * SEQ  + quad * 8;

        #pragma unroll 1
        for (int wt = 0; wt < 2; ++wt) {
            const int t  = wt ? (127 - pr) : pr;
            const int s0 = t * 16;
            const int nch  = (t + 2) >> 1;           // ceil(16(t+1)/32)
            const int c0   = (nch * wv) >> 2;
            const int c1   = (nch * (wv + 1)) >> 2;
            const int cmax = (nch + 3) >> 2;         // uniform per block

            const short* qb = q + ((long)b * SEQ + s0 + l15) * HEAD + quad * 8;
            short8 qf0 = *(const short8*)(qb);
            short8 qf1 = *(const short8*)(qb + 32);

            floatx4 o[4];
            #pragma unroll
            for (int nt = 0; nt < 4; ++nt) o[nt] = (floatx4){0.f, 0.f, 0.f, 0.f};
            float l_i[4] = {0.f, 0.f, 0.f, 0.f};

            #pragma unroll 2
            for (int i = 0; i < cmax; ++i) {
                const int c = c0 + i;
                const bool act = (c < c1);
                const int j0 = c * 32;               // always in-bounds

                floatx4 sa[2];
                sa[0] = (floatx4){0.f, 0.f, 0.f, 0.f};
                sa[1] = (floatx4){0.f, 0.f, 0.f, 0.f};
                #pragma unroll
                for (int nt = 0; nt < 2; ++nt) {
                    const short* kb = kbb + (long)(j0 + nt * 16) * HEAD;
                    short8 kf0 = *(const short8*)(kb);
                    short8 kf1 = *(const short8*)(kb + 32);
                    sa[nt] = __builtin_amdgcn_mfma_f32_16x16x32_bf16(qf0, kf0, sa[nt], 0, 0, 0);
                    sa[nt] = __builtin_amdgcn_mfma_f32_16x16x32_bf16(qf1, kf1, sa[nt], 0, 0, 0);
                }

                #pragma unroll
                for (int r = 0; r < 4; ++r) {
                    const int sq = s0 + quad * 4 + r;
                    #pragma unroll
                    for (int nt = 0; nt < 2; ++nt) {
                        const int sk = j0 + nt * 16 + l15;
                        float p = (!act || sk > sq) ? 0.f
                                  : __expf(sa[nt][r] * 0.125f - 16.f);
                        sa[nt][r] = p;
                        l_i[r] += p;
                    }
                }

                // P: C-layout -> A-layout via per-wave LDS (wave-local, no barrier)
                #pragma unroll
                for (int nt = 0; nt < 2; ++nt)
                    #pragma unroll
                    for (int r = 0; r < 4; ++r)
                        Plds[wv][quad * 4 + r][nt * 16 + l15] = f2bf(sa[nt][r]);
                short8 pf = *(const short8*)(&Plds[wv][l15][quad * 8]);

                #pragma unroll
                for (int nt = 0; nt < 4; ++nt) {
                    short8 vf = *(const short8*)(vbb + (long)nt * 16 * SEQ + j0);
                    o[nt] = __builtin_amdgcn_mfma_f32_16x16x32_bf16(pf, vf, o[nt], 0, 0, 0);
                }
            }

            // single end-of-loop l reduction (16 lanes sharing a quad-row)
            #pragma unroll
            for (int msk = 1; msk <= 8; msk <<= 1) {
                #pragma unroll
                for (int r = 0; r < 4; ++r)
                    l_i[r] += __shfl_xor(l_i[r], msk, 64);
            }
            if (l15 == 0) {
                #pragma unroll
                for (int r = 0; r < 4; ++r) lA[wv][quad * 4 + r] = l_i[r];
            }
            #pragma unroll
            for (int nt = 0; nt < 4; ++nt)
                #pragma unroll
                for (int r = 0; r < 4; ++r)
                    oA[wv][quad * 4 + r][nt * 16 + l15] = o[nt][r];
            __syncthreads();

            // cooperative epilogue: sum 4 wave-partials, coalesced float4 out
            {
                const int idx = tid * 4;             // 1024 outputs, 4/thread
                const int row = idx >> 6;
                const int col = idx & 63;
                const float l = lA[0][row] + lA[1][row] + lA[2][row] + lA[3][row];
                const float inv = 1.f / l;
                floatx4 ov;
                #pragma unroll
                for (int j = 0; j < 4; ++j)
                    ov[j] = (oA[0][row][col + j] + oA[1][row][col + j]
                           + oA[2][row][col + j] + oA[3][row][col + j]) * inv;
                *(floatx4*)(out + ((long)b * SEQ + s0 + row) * HEAD + col) = ov;
            }
            __syncthreads();   // protect LDS before next tile overwrites
        }
    }
}

extern "C" void kernel_launch(void* const* d_in, const int* in_sizes, int n_in,
                              void* d_out, int out_size, void* d_ws, size_t ws_size,
                              hipStream_t stream) {
    const float* x  = (const float*)d_in[0];
    const float* Wk = (const float*)d_in[1];
    const float* Wq = (const float*)d_in[2];
    const float* Wv = (const float*)d_in[3];
    float* out = (float*)d_out;

    short* Wf = (short*)d_ws;                          // 384 KiB
    short* q  = Wf + 3 * HEAD * EMB;                   // 2 MiB each
    short* k  = q + (long)BATCH * SEQ * HEAD;
    short* vt = k + (long)BATCH * SEQ * HEAD;

    void* args[] = { (void*)&x, (void*)&Wk, (void*)&Wq, (void*)&Wv,
                     (void*)&out, (void*)&Wf, (void*)&q, (void*)&k, (void*)&vt };
    hipLaunchCooperativeKernel(fused_kernel, dim3(512), dim3(256),
                               args, 0u, stream);
}

// Round 7
// 158.245 us; speedup vs baseline: 1.6968x; 1.6968x over previous
//
#include <hip/hip_runtime.h>
#include <hip/hip_bf16.h>

typedef __attribute__((ext_vector_type(8))) short short8;
typedef __attribute__((ext_vector_type(4))) short short4v;
typedef __attribute__((ext_vector_type(4))) float floatx4;

#define SEQ   2048
#define EMB   1024
#define HEAD  64
#define BATCH 8

__device__ __forceinline__ short f2bf(float f) {
    union { float f; unsigned u; } a; a.f = f;
    unsigned u = a.u;
    u = (u + 0x7FFFu + ((u >> 16) & 1u)) >> 16;   // round-to-nearest-even
    return (short)u;
}

// Wf: MFMA-fragment-ordered weights, bf16.
// fragid f = (mat*4 + nt)*32 + kchunk, mat 0=Wq 1=Wk 2=Wv.
// Wf[f*512 + lane*8 + j] = W[k = kchunk*32 + (lane>>4)*8 + j][h = nt*16 + (lane&15)]
__global__ void wtrans_kernel(const float* __restrict__ Wk,
                              const float* __restrict__ Wq,
                              const float* __restrict__ Wv,
                              short* __restrict__ Wf) {
    int gid  = blockIdx.x * 256 + threadIdx.x;   // 24576 total
    int lane = gid & 63;
    int fid  = gid >> 6;
    int chunk = fid & 31;
    int mnt  = fid >> 5;
    int mat  = mnt >> 2, nt = mnt & 3;
    const float* src = (mat == 0) ? Wq : (mat == 1) ? Wk : Wv;
    int n = lane & 15, quad = lane >> 4;
    int h = nt * 16 + n;
    short8 o8;
    #pragma unroll
    for (int j = 0; j < 8; ++j)
        o8[j] = f2bf(src[(chunk * 32 + quad * 8 + j) * 64 + h]);
    *(short8*)(Wf + (long)gid * 8) = o8;
}

// Block: 16 rows x 192 cols, 4 waves split K into quarters; LDS reduce.
// sched_barrier(0) fences force ALL 12 B-frag + 2 x loads to issue as one
// cluster before any consumer -> one L2 latency per iter, 48+ live VGPRs.
__global__ __launch_bounds__(256, 3) void qkv_kernel(const float* __restrict__ x,
                                                     const short* __restrict__ Wf,
                                                     short* __restrict__ q,
                                                     short* __restrict__ k,
                                                     short* __restrict__ vt) {
    __shared__ float red[3][64][50];   // stride 50: 2-way bank alias (free)
    const int wv   = threadIdx.x >> 6;
    const int lane = threadIdx.x & 63;
    const int l15  = lane & 15;
    const int quad = lane >> 4;
    const int row0 = blockIdx.x * 16;

    floatx4 acc[12];
    #pragma unroll
    for (int f = 0; f < 12; ++f) acc[f] = (floatx4){0.f, 0.f, 0.f, 0.f};

    const float* xrow  = x + (long)(row0 + l15) * EMB + quad * 8;
    const short* wlane = Wf + (long)lane * 8;
    const int kbase = wv * 256;

    floatx4 xa = *(const floatx4*)(xrow + kbase);
    floatx4 xb = *(const floatx4*)(xrow + kbase + 4);

    #pragma unroll 1
    for (int kk = 0; kk < 256; kk += 32) {
        const int cidx = (kbase + kk) >> 5;

        __builtin_amdgcn_sched_barrier(0);
        // ---- load cluster: 12 B fragments + next x chunk ----
        short8 bfr[12];
        #pragma unroll
        for (int f = 0; f < 12; ++f)
            bfr[f] = *(const short8*)(wlane + (long)(f * 32 + cidx) * 512);
        const int kn = kbase + ((kk + 32) & 255);   // wraps: safe, cached
        floatx4 na = *(const floatx4*)(xrow + kn);
        floatx4 nb = *(const floatx4*)(xrow + kn + 4);
        __builtin_amdgcn_sched_barrier(0);

        short8 a;
        #pragma unroll
        for (int i = 0; i < 4; ++i) { a[i] = f2bf(xa[i]); a[4 + i] = f2bf(xb[i]); }
        #pragma unroll
        for (int f = 0; f < 12; ++f)
            acc[f] = __builtin_amdgcn_mfma_f32_16x16x32_bf16(a, bfr[f], acc[f], 0, 0, 0);
        xa = na; xb = nb;
    }

    if (wv > 0) {
        #pragma unroll
        for (int f = 0; f < 12; ++f)
            #pragma unroll
            for (int r = 0; r < 4; ++r)
                red[wv - 1][lane][f * 4 + r] = acc[f][r];
    }
    __syncthreads();
    if (wv == 0) {
        #pragma unroll
        for (int w = 0; w < 3; ++w)
            #pragma unroll
            for (int f = 0; f < 12; ++f)
                #pragma unroll
                for (int r = 0; r < 4; ++r)
                    acc[f][r] += red[w][lane][f * 4 + r];

        const int bidx = row0 >> 11;
        const int srow = (row0 & (SEQ - 1)) + quad * 4;
        #pragma unroll
        for (int nt = 0; nt < 4; ++nt) {
            const int col = nt * 16 + l15;
            #pragma unroll
            for (int r = 0; r < 4; ++r) {
                long grow = (long)(row0 + quad * 4 + r);
                q[grow * HEAD + col] = f2bf(acc[nt][r]);
                k[grow * HEAD + col] = f2bf(acc[4 + nt][r]);
            }
            short4v vv;
            #pragma unroll
            for (int r = 0; r < 4; ++r) vv[r] = f2bf(acc[8 + nt][r]);
            *(short4v*)(vt + ((long)bidx * HEAD + col) * SEQ + srow) = vv;
        }
    }
}

// Flash attention, causal, fixed-base softmax exp(s/8-16) (row-max >= 0 via
// causal diagonal; base cancels in sum(pV)/sum(p)). 4 waves key-split one
// 16-row tile. sched_barrier forces the 8 K/V fragment loads to issue as one
// cluster at iter top -> one L2 round-trip per iter.
__global__ __launch_bounds__(256, 3) void attn_kernel(const short* __restrict__ q,
                                                      const short* __restrict__ k,
                                                      const short* __restrict__ vt,
                                                      float* __restrict__ out) {
    __shared__ short Plds[4][16][40];   // pad 40: cuts bank conflicts (R6)
    __shared__ float oA[4][16][64];
    __shared__ float lA[4][16];

    const int wv   = threadIdx.x >> 6;
    const int lane = threadIdx.x & 63;
    const int l15  = lane & 15;
    const int quad = lane >> 4;
    const int b    = blockIdx.x & 7;
    const int t    = 127 - (blockIdx.x >> 3);
    const int s0   = t * 16;

    const int nch  = (t + 2) >> 1;          // ceil(16(t+1)/32)
    const int c0   = (nch * wv) >> 2;
    const int c1   = (nch * (wv + 1)) >> 2;
    const int cmax = (nch + 3) >> 2;        // uniform loop count per block

    const short* qb = q + ((long)b * SEQ + s0 + l15) * HEAD + quad * 8;
    short8 qf0 = *(const short8*)(qb);
    short8 qf1 = *(const short8*)(qb + 32);

    const short* kbb = k  + ((long)b * SEQ  + l15) * HEAD + quad * 8;
    const short* vbb = vt + ((long)b * HEAD + l15) * SEQ  + quad * 8;

    floatx4 o[4];
    #pragma unroll
    for (int nt = 0; nt < 4; ++nt) o[nt] = (floatx4){0.f, 0.f, 0.f, 0.f};
    float l_i[4] = {0.f, 0.f, 0.f, 0.f};

    #pragma unroll 1
    for (int i = 0; i < cmax; ++i) {
        const int c = c0 + i;
        const bool act = (c < c1);
        const int j0 = c * 32;              // always in-bounds

        __builtin_amdgcn_sched_barrier(0);
        // ---- load cluster: 4 K frags + 4 V frags ----
        short8 kf[2][2], vf[4];
        #pragma unroll
        for (int nt = 0; nt < 2; ++nt) {
            const short* kb = kbb + (long)(j0 + nt * 16) * HEAD;
            kf[nt][0] = *(const short8*)(kb);
            kf[nt][1] = *(const short8*)(kb + 32);
        }
        #pragma unroll
        for (int nt = 0; nt < 4; ++nt)
            vf[nt] = *(const short8*)(vbb + (long)nt * 16 * SEQ + j0);
        __builtin_amdgcn_sched_barrier(0);

        // ---- S = Q K^T ----
        floatx4 sa[2];
        sa[0] = (floatx4){0.f, 0.f, 0.f, 0.f};
        sa[1] = (floatx4){0.f, 0.f, 0.f, 0.f};
        #pragma unroll
        for (int nt = 0; nt < 2; ++nt) {
            sa[nt] = __builtin_amdgcn_mfma_f32_16x16x32_bf16(qf0, kf[nt][0], sa[nt], 0, 0, 0);
            sa[nt] = __builtin_amdgcn_mfma_f32_16x16x32_bf16(qf1, kf[nt][1], sa[nt], 0, 0, 0);
        }

        // ---- p = exp(s/8 - 16), causal + activity mask; accumulate l ----
        #pragma unroll
        for (int r = 0; r < 4; ++r) {
            const int sq = s0 + quad * 4 + r;
            #pragma unroll
            for (int nt = 0; nt < 2; ++nt) {
                const int sk = j0 + nt * 16 + l15;
                float p = (!act || sk > sq) ? 0.f
                          : __expf(sa[nt][r] * 0.125f - 16.f);
                sa[nt][r] = p;
                l_i[r] += p;
            }
        }

        // ---- P: C-layout -> A-layout via per-wave LDS (no barrier) ----
        #pragma unroll
        for (int nt = 0; nt < 2; ++nt)
            #pragma unroll
            for (int r = 0; r < 4; ++r)
                Plds[wv][quad * 4 + r][nt * 16 + l15] = f2bf(sa[nt][r]);
        short8 pf = *(const short8*)(&Plds[wv][l15][quad * 8]);

        // ---- O += P V (vf already resident) ----
        #pragma unroll
        for (int nt = 0; nt < 4; ++nt)
            o[nt] = __builtin_amdgcn_mfma_f32_16x16x32_bf16(pf, vf[nt], o[nt], 0, 0, 0);
    }

    // ---- single end-of-loop l reduction ----
    #pragma unroll
    for (int msk = 1; msk <= 8; msk <<= 1) {
        #pragma unroll
        for (int r = 0; r < 4; ++r)
            l_i[r] += __shfl_xor(l_i[r], msk, 64);
    }
    if (l15 == 0) {
        #pragma unroll
        for (int r = 0; r < 4; ++r) lA[wv][quad * 4 + r] = l_i[r];
    }
    #pragma unroll
    for (int nt = 0; nt < 4; ++nt)
        #pragma unroll
        for (int r = 0; r < 4; ++r)
            oA[wv][quad * 4 + r][nt * 16 + l15] = o[nt][r];
    __syncthreads();

    // ---- cooperative epilogue: sum 4 wave-partials, coalesced float4 out ----
    {
        const int idx = threadIdx.x * 4;         // 1024 outputs, 4 per thread
        const int row = idx >> 6;
        const int col = idx & 63;
        const float l = lA[0][row] + lA[1][row] + lA[2][row] + lA[3][row];
        const float inv = 1.f / l;
        floatx4 ov;
        #pragma unroll
        for (int j = 0; j < 4; ++j)
            ov[j] = (oA[0][row][col + j] + oA[1][row][col + j]
                   + oA[2][row][col + j] + oA[3][row][col + j]) * inv;
        *(floatx4*)(out + ((long)b * SEQ + s0 + row) * HEAD + col) = ov;
    }
}

extern "C" void kernel_launch(void* const* d_in, const int* in_sizes, int n_in,
                              void* d_out, int out_size, void* d_ws, size_t ws_size,
                              hipStream_t stream) {
    const float* x  = (const float*)d_in[0];
    const float* Wk = (const float*)d_in[1];
    const float* Wq = (const float*)d_in[2];
    const float* Wv = (const float*)d_in[3];
    float* out = (float*)d_out;

    short* Wf = (short*)d_ws;                          // 384 KiB
    short* q  = Wf + 3 * HEAD * EMB;                   // 2 MiB each
    short* k  = q + (long)BATCH * SEQ * HEAD;
    short* vt = k + (long)BATCH * SEQ * HEAD;

    hipLaunchKernelGGL(wtrans_kernel, dim3(96), dim3(256), 0, stream, Wk, Wq, Wv, Wf);
    hipLaunchKernelGGL(qkv_kernel, dim3(BATCH * SEQ / 16), dim3(256), 0, stream, x, Wf, q, k, vt);
    hipLaunchKernelGGL(attn_kernel, dim3(BATCH * 128), dim3(256), 0, stream, q, k, vt, out);
}